// Round 10
// baseline (10131.046 us; speedup 1.0000x reference)
//
#include <hip/hip_runtime.h>

// ---------------- problem constants ----------------
#define T_LEN 128
// ws layout (bytes)
#define WF_OFF 0            // W frags: 2*8*8*10*64*16 = 1,310,720
#define BI_OFF 1310720      // bias frags: 2*8*8*64*16 = 131,072
#define XZ_OFF 1441792      // xz: 16*128*64*64*2 = 16,777,216
#define HZ_OFF 18219008     // hz: 32*2*64*256*2 = 2,097,152
#define FL_OFF 20316160     // flags: 32*128*4 = 16,384
#define WS_END 20332544

typedef short bf16x8 __attribute__((ext_vector_type(8)));
typedef float f32x4 __attribute__((ext_vector_type(4)));

#define WAITV0 asm volatile("s_waitcnt vmcnt(0)" ::: "memory")

__device__ __forceinline__ short f32_to_bf16(float f) {
  unsigned u = __float_as_uint(f);
  unsigned r = u + 0x7FFFu + ((u >> 16) & 1u);   // RNE
  return (short)(r >> 16);
}
__device__ __forceinline__ float sigmoidf_fast(float x) {
  return 1.0f / (1.0f + __expf(-x));
}
__device__ __forceinline__ float tanhf_fast(float x) {
  return 1.0f - 2.0f / (__expf(2.0f * x) + 1.0f);
}

// async 16B/lane global->LDS DMA (LDS dest wave-uniform + lane*16)
__device__ __forceinline__ void gll16(const void* g, char* lds_generic) {
  __builtin_amdgcn_global_load_lds(
      (const __attribute__((address_space(1))) void*)g,
      (__attribute__((address_space(3))) void*)lds_generic, 16, 0, 0);
}
// asm-pinned prologue loads (un-sinkable; small count -> no spill pressure)
__device__ __forceinline__ bf16x8 ald16(const void* p) {
  bf16x8 d;
  asm volatile("global_load_dwordx4 %0, %1, off" : "=v"(d) : "v"(p));
  return d;
}
__device__ __forceinline__ f32x4 aldf4(const void* p) {
  f32x4 d;
  asm volatile("global_load_dwordx4 %0, %1, off" : "=v"(d) : "v"(p));
  return d;
}

// ---------------- prep: pack W (unit-major rows) ----------------
// wf[dir][m][mtl][kt][lane][8 bf16]. WG m owns units [32m,32m+32).
// A-frag: lane row rA = l&15, k = kt*32 + (l>>4)*8 + e.
// torch row for (mtl, rA) = (rA&3)*256 + 32m + 4*mtl + (rA>>2)
// (gate = rA&3 in i,f,g,o order; unit_local = 4*mtl + rA>>2).
__global__ void pack_w(const float* __restrict__ Wih_f, const float* __restrict__ Whh_f,
                       const float* __restrict__ Wih_b, const float* __restrict__ Whh_b,
                       short* __restrict__ wf) {
  int t = blockIdx.x * blockDim.x + threadIdx.x;   // 81920 exact
  int l = t & 63;
  int r1 = t >> 6;          // 1280
  int kt = r1 % 10;
  int r2 = r1 / 10;         // 128
  int mtl = r2 & 7;
  int r3 = r2 >> 3;         // 16
  int m = r3 & 7;
  int dir = r3 >> 3;
  const float* Wih = dir ? Wih_b : Wih_f;
  const float* Whh = dir ? Whh_b : Whh_f;
  int rA = l & 15;
  int row = (rA & 3) * 256 + 32 * m + 4 * mtl + (rA >> 2);
  int kb = kt * 32 + (l >> 4) * 8;
  bf16x8 v;
#pragma unroll
  for (int e = 0; e < 8; ++e) {
    int k = kb + e;
    float f = (k < 64) ? Wih[row * 64 + k] : Whh[row * 256 + (k - 64)];
    v[e] = f32_to_bf16(f);
  }
  long idx = ((((long)dir * 8 + m) * 8 + mtl) * 10 + kt) * 64 + l;
  *reinterpret_cast<bf16x8*>(wf + idx * 8) = v;
}

// bias frag per (dir,m,mtl,lane): f32x4 = gates i,f,g,o of unit 32m+4*mtl+lg
__global__ void pack_bias(const float* __restrict__ bihf, const float* __restrict__ bhhf,
                          const float* __restrict__ bihb, const float* __restrict__ bhhb,
                          float* __restrict__ bp) {
  int t = blockIdx.x * blockDim.x + threadIdx.x;   // 8192 exact
  int l = t & 63;
  int mtl = (t >> 6) & 7;
  int m = (t >> 9) & 7;
  int dir = (t >> 12) & 1;
  const float* bih = dir ? bihb : bihf;
  const float* bhh = dir ? bhhb : bhhf;
  int u = 32 * m + 4 * mtl + ((l >> 4) & 3);
  f32x4 v;
#pragma unroll
  for (int r = 0; r < 4; ++r) v[r] = bih[r * 256 + u] + bhh[r * 256 + u];
  long idx = (((long)dir * 8 + m) * 8 + mtl) * 64 + l;
  *reinterpret_cast<f32x4*>(bp + idx * 4) = v;
}

// xz[s 16][t 128][a 64][c 64] bf16  (batch block = one sample, Nb=64)
__global__ void pack_x(const float* __restrict__ x, short* __restrict__ xz) {
  int t = blockIdx.x * blockDim.x + threadIdx.x;   // 2^20 exact
  int cs = t & 7;
  int a  = (t >> 3) & 63;
  int tt = (t >> 9) & 127;
  int s  = (t >> 16) & 15;
  bf16x8 v;
#pragma unroll
  for (int e = 0; e < 8; ++e) {
    int c = cs * 8 + e;
    v[e] = f32_to_bf16(x[(((long)s * 64 + c) * 128 + tt) * 64 + a]);
  }
  long idx = (((long)s * 128 + tt) * 64 + a) * 64 + cs * 8;
  *reinterpret_cast<bf16x8*>(xz + idx) = v;
}

// ---------------- the recurrent kernel ----------------
// grid 256 = g(32, bid&31) x m(8, bid>>5). Group g: dir = g&1, sample bb =
// g>>1. WG m owns units [32m,32m+32). LDS 45KB -> >=3 WG/CU capacity ->
// all 256 WGs resident unconditionally (no co-residency gamble).
// Per step: acquire (flag spin + threadfence) -> stage z(t) = [x 8KB | h 32KB]
// into 40x1KB LDS frags via gll16 -> 10kt x 4nt MFMA vs 40 pinned W regs ->
// epilogue -> htr -> publish h slice (normal stores) + out -> release
// (threadfence = drain + L2 writeback) -> flag add (agent-scope RMW).
// No hand sc-bits, no hand vmcnt ledger; register demand ~90 << 128 cap.
__global__ __launch_bounds__(512) void lstm_rec(
    const short* __restrict__ wf, const float* __restrict__ bp,
    const short* __restrict__ xz, short* __restrict__ hz,
    int* __restrict__ flags, float* __restrict__ out) {
  __shared__ __align__(16) char zbuf[40960];   // 40 frags x 1KB
  __shared__ __align__(16) char htr[4096];     // [a 64][u_l 32] bf16

  const int bid = blockIdx.x;
  const int m = bid >> 5, g = bid & 31;
  const int dir = g & 1, bb = g >> 1;
  const int tid = threadIdx.x;
  const int w = tid >> 6, l = tid & 63;
  const int lg = l >> 4, ln = l & 15;

  // ---- prologue: pin W (10 frags = 40 VGPR) + bias via asm loads ----
  const char* wslice = (const char*)wf +
      ((((long)dir * 8 + m) * 8 + w) * 10) * 1024 + (long)l * 16;
  bf16x8 W0[10];
#pragma unroll
  for (int kt = 0; kt < 10; ++kt) W0[kt] = ald16(wslice + kt * 1024);
  const f32x4 bias4 = aldf4((const char*)bp +
      (((((long)dir * 8 + m) * 8 + w) * 64 + l) * 16));
  WAITV0;

  const char* xzb = (const char*)xz + (long)bb * (128L * 64 * 64 * 2);
  char* const hzg = (char*)hz + (long)g * (2L * 64 * 256 * 2);
  int* const flg = flags + g * T_LEN;

  float cst[4] = {0.f, 0.f, 0.f, 0.f};

  for (int st = 0; st < T_LEN; ++st) {
    const int t = dir ? (T_LEN - 1 - st) : st;

    // ---- acquire: partners' h(st-1) published ----
    if (st > 0 && tid == 0) {
      while (__hip_atomic_load(flg + (st - 1), __ATOMIC_RELAXED,
                               __HIP_MEMORY_SCOPE_AGENT) < 8)
        __builtin_amdgcn_s_sleep(2);
    }
    __syncthreads();
    __threadfence();   // acquire side: invalidate stale caches

    // ---- stage z(t): wave w stages frags 5w..5w+4 (f = kt*4+nt) ----
    {
      const char* xstep = xzb + (long)t * (64 * 64 * 2);
      const char* hprev = hzg + (long)((st + 1) & 1) * (64 * 256 * 2);
#pragma unroll
      for (int j = 0; j < 5; ++j) {
        const int f = 5 * w + j, kt = f >> 2, nt = f & 3;
        const char* src = (f < 8)
            ? xstep + (long)(((nt * 16 + ln) * 64 + kt * 32 + lg * 8) * 2)
            : hprev + (long)(((nt * 16 + ln) * 256 + (kt - 2) * 32 + lg * 8) * 2);
        gll16(src, zbuf + f * 1024);
      }
    }
    WAITV0;
    __syncthreads();

    // ---- MFMA: 10 kt x 4 nt, W pinned, B from LDS ----
    f32x4 acc[4];
#pragma unroll
    for (int nt = 0; nt < 4; ++nt) acc[nt] = bias4;
#pragma unroll
    for (int kt = 0; kt < 10; ++kt)
#pragma unroll
      for (int nt = 0; nt < 4; ++nt) {
        bf16x8 b = *reinterpret_cast<const bf16x8*>(
            zbuf + (kt * 4 + nt) * 1024 + l * 16);
        acc[nt] = __builtin_amdgcn_mfma_f32_16x16x32_bf16(W0[kt], b, acc[nt], 0, 0, 0);
      }

    // ---- epilogue (lane-local: regs 0..3 = gates i,f,g,o) ----
    float hv[4];
#pragma unroll
    for (int nt = 0; nt < 4; ++nt) {
      float gi = sigmoidf_fast(acc[nt][0]);
      float gf = sigmoidf_fast(acc[nt][1]);
      float gg = tanhf_fast(acc[nt][2]);
      float go = sigmoidf_fast(acc[nt][3]);
      float cc = gf * cst[nt] + gi * gg;
      cst[nt] = cc;
      hv[nt] = go * tanhf_fast(cc);
    }
#pragma unroll
    for (int nt = 0; nt < 4; ++nt)
      *reinterpret_cast<short*>(htr + (nt * 16 + ln) * 64 + (4 * w + lg) * 2) =
          f32_to_bf16(hv[nt]);
    __syncthreads();

    // ---- publish h slice (normal stores) + out stores ----
    char* hcur = hzg + (long)(st & 1) * (64 * 256 * 2);
    if (tid < 256) {
      const int a = tid >> 2, seg = tid & 3;
      bf16x8 v = *reinterpret_cast<const bf16x8*>(htr + tid * 16);
      *reinterpret_cast<bf16x8*>(hcur + (long)((a * 256 + 32 * m + seg * 8) * 2)) = v;
    }
    {
      const long hrow = (long)dir * 256 + 32 * m + 4 * w + lg;
#pragma unroll
      for (int nt = 0; nt < 4; ++nt) {
        const int a = nt * 16 + ln;
        out[(((long)bb * 512 + hrow) * 128 + t) * 64 + a] = hv[nt];
      }
    }
    __threadfence();   // release: drain stores + L2 writeback
    __syncthreads();   // all threads' fences done before flag post
    if (tid == 0)
      __hip_atomic_fetch_add(flg + st, 1, __ATOMIC_RELEASE,
                             __HIP_MEMORY_SCOPE_AGENT);
  }
}

// ---------------- launcher ----------------
extern "C" void kernel_launch(void* const* d_in, const int* in_sizes, int n_in,
                              void* d_out, int out_size, void* d_ws, size_t ws_size,
                              hipStream_t stream) {
  const float* x     = (const float*)d_in[0];
  const float* Wih_f = (const float*)d_in[1];
  const float* Whh_f = (const float*)d_in[2];
  const float* bih_f = (const float*)d_in[3];
  const float* bhh_f = (const float*)d_in[4];
  const float* Wih_b = (const float*)d_in[5];
  const float* Whh_b = (const float*)d_in[6];
  const float* bih_b = (const float*)d_in[7];
  const float* bhh_b = (const float*)d_in[8];
  float* out = (float*)d_out;

  char* ws = (char*)d_ws;
  short* wf    = (short*)(ws + WF_OFF);
  float* bp    = (float*)(ws + BI_OFF);
  short* xz    = (short*)(ws + XZ_OFF);
  short* hz    = (short*)(ws + HZ_OFF);
  int*   flags = (int*)(ws + FL_OFF);

  hipLaunchKernelGGL(pack_w, dim3(320), dim3(256), 0, stream,
                     Wih_f, Whh_f, Wih_b, Whh_b, wf);
  hipLaunchKernelGGL(pack_bias, dim3(32), dim3(256), 0, stream,
                     bih_f, bhh_f, bih_b, bhh_b, bp);
  hipLaunchKernelGGL(pack_x, dim3(4096), dim3(256), 0, stream, x, xz);
  // zero hz (h(-1)=0) + flags every launch (determinism across graph replays)
  hipMemsetAsync(ws + HZ_OFF, 0, WS_END - HZ_OFF, stream);
  hipLaunchKernelGGL(lstm_rec, dim3(256), dim3(512), 0, stream,
                     wf, bp, xz, hz, flags, out);
}

// Round 11
// 627.419 us; speedup vs baseline: 16.1472x; 16.1472x over previous
//
#include <hip/hip_runtime.h>

// ---------------- problem constants ----------------
#define T_LEN 128
// ws layout (bytes)
#define WF_OFF 0            // W frags: 2*8*8*10*64*16 = 1,310,720
#define BI_OFF 1310720      // bias frags: 2*8*8*64*16 = 131,072
#define XZ_OFF 1441792      // xz: 16*128*64*64*2 = 16,777,216
#define HZ_OFF 18219008     // hz: 32*2*64*256*2 = 2,097,152
#define FL_OFF 20316160     // flags: 32*128*4 = 16,384
#define WS_END 20332544

typedef short bf16x8 __attribute__((ext_vector_type(8)));
typedef float f32x4 __attribute__((ext_vector_type(4)));

#define WAITV0 asm volatile("s_waitcnt vmcnt(0)" ::: "memory")
#define SCHB __builtin_amdgcn_sched_barrier(0)

__device__ __forceinline__ short f32_to_bf16(float f) {
  unsigned u = __float_as_uint(f);
  unsigned r = u + 0x7FFFu + ((u >> 16) & 1u);   // RNE
  return (short)(r >> 16);
}
__device__ __forceinline__ float sigmoidf_fast(float x) {
  return 1.0f / (1.0f + __expf(-x));
}
__device__ __forceinline__ float tanhf_fast(float x) {
  return 1.0f - 2.0f / (__expf(2.0f * x) + 1.0f);
}

// async 16B/lane global->LDS DMA (LDS dest wave-uniform + lane*16)
__device__ __forceinline__ void gll16(const void* g, char* lds_generic) {
  __builtin_amdgcn_global_load_lds(
      (const __attribute__((address_space(1))) void*)g,
      (__attribute__((address_space(3))) void*)lds_generic, 16, 0, 0);
}
// asm-pinned loads (un-sinkable)
__device__ __forceinline__ bf16x8 ald16(const void* p) {
  bf16x8 d;
  asm volatile("global_load_dwordx4 %0, %1, off" : "=v"(d) : "v"(p));
  return d;
}
__device__ __forceinline__ f32x4 aldf4(const void* p) {
  f32x4 d;
  asm volatile("global_load_dwordx4 %0, %1, off" : "=v"(d) : "v"(p));
  return d;
}
// device-scope (coherence point) load/store: bypass per-XCD L2
__device__ __forceinline__ bf16x8 ald16_dev(const void* p) {
  bf16x8 d;
  asm volatile("global_load_dwordx4 %0, %1, off sc0 sc1" : "=v"(d) : "v"(p));
  return d;
}
__device__ __forceinline__ void ast16_dev(void* p, bf16x8 v) {
  asm volatile("global_store_dwordx4 %0, %1, off sc0 sc1" :: "v"(p), "v"(v));
}

// ---------------- prep: pack W (unit-major rows) ----------------
// wf[dir][m][mtl][kt][lane][8 bf16]. WG m owns units [32m,32m+32).
// A-frag: lane row rA = l&15, k = kt*32 + (l>>4)*8 + e.
// torch row for (mtl, rA) = (rA&3)*256 + 32m + 4*mtl + (rA>>2)
// (gate = rA&3 in i,f,g,o order; unit_local = 4*mtl + rA>>2).
__global__ void pack_w(const float* __restrict__ Wih_f, const float* __restrict__ Whh_f,
                       const float* __restrict__ Wih_b, const float* __restrict__ Whh_b,
                       short* __restrict__ wf) {
  int t = blockIdx.x * blockDim.x + threadIdx.x;   // 81920 exact
  int l = t & 63;
  int r1 = t >> 6;          // 1280
  int kt = r1 % 10;
  int r2 = r1 / 10;         // 128
  int mtl = r2 & 7;
  int r3 = r2 >> 3;         // 16
  int m = r3 & 7;
  int dir = r3 >> 3;
  const float* Wih = dir ? Wih_b : Wih_f;
  const float* Whh = dir ? Whh_b : Whh_f;
  int rA = l & 15;
  int row = (rA & 3) * 256 + 32 * m + 4 * mtl + (rA >> 2);
  int kb = kt * 32 + (l >> 4) * 8;
  bf16x8 v;
#pragma unroll
  for (int e = 0; e < 8; ++e) {
    int k = kb + e;
    float f = (k < 64) ? Wih[row * 64 + k] : Whh[row * 256 + (k - 64)];
    v[e] = f32_to_bf16(f);
  }
  long idx = ((((long)dir * 8 + m) * 8 + mtl) * 10 + kt) * 64 + l;
  *reinterpret_cast<bf16x8*>(wf + idx * 8) = v;
}

// bias frag per (dir,m,mtl,lane): f32x4 = gates i,f,g,o of unit 32m+4*mtl+lg
__global__ void pack_bias(const float* __restrict__ bihf, const float* __restrict__ bhhf,
                          const float* __restrict__ bihb, const float* __restrict__ bhhb,
                          float* __restrict__ bp) {
  int t = blockIdx.x * blockDim.x + threadIdx.x;   // 8192 exact
  int l = t & 63;
  int mtl = (t >> 6) & 7;
  int m = (t >> 9) & 7;
  int dir = (t >> 12) & 1;
  const float* bih = dir ? bihb : bihf;
  const float* bhh = dir ? bhhb : bhhf;
  int u = 32 * m + 4 * mtl + ((l >> 4) & 3);
  f32x4 v;
#pragma unroll
  for (int r = 0; r < 4; ++r) v[r] = bih[r * 256 + u] + bhh[r * 256 + u];
  long idx = (((long)dir * 8 + m) * 8 + mtl) * 64 + l;
  *reinterpret_cast<f32x4*>(bp + idx * 4) = v;
}

// xz[s 16][t 128][a 64][c 64] bf16  (batch block = one sample, Nb=64)
__global__ void pack_x(const float* __restrict__ x, short* __restrict__ xz) {
  int t = blockIdx.x * blockDim.x + threadIdx.x;   // 2^20 exact
  int cs = t & 7;
  int a  = (t >> 3) & 63;
  int tt = (t >> 9) & 127;
  int s  = (t >> 16) & 15;
  bf16x8 v;
#pragma unroll
  for (int e = 0; e < 8; ++e) {
    int c = cs * 8 + e;
    v[e] = f32_to_bf16(x[(((long)s * 64 + c) * 128 + tt) * 64 + a]);
  }
  long idx = (((long)s * 128 + tt) * 64 + a) * 64 + cs * 8;
  *reinterpret_cast<bf16x8*>(xz + idx) = v;
}

// ---------------- the recurrent kernel ----------------
// grid 256 = g(32, bid&31) x m(8, bid>>5). Group g: dir = g&1, sample bb =
// g>>1. WG m owns units [32m,32m+32). LDS 44KB -> >=3 WG/CU capacity ->
// all 256 WGs resident unconditionally.
// Exchange (R10 structure, fences removed): publish h via sc0sc1 stores
// (write-through to coherence point; NO L2 flush), drain vmcnt(0), barrier,
// RELAXED agent-scope flag add. Read partners' h via sc0sc1 register loads
// (bypass stale L2) + ds_write into zbuf. x staged via gll16 (read-only, L2
// caching fine). st=0 stages literal zeros for h (h(-1)=0) so hz needs no
// memset (avoids dirty-L2-vs-bypass-read staleness hazard).
// K-order per output elem: bias, kt0,1 (x), kt2..9 (h) == R10 -> absmax equal.
__global__ __launch_bounds__(512) void lstm_rec(
    const short* __restrict__ wf, const float* __restrict__ bp,
    const short* __restrict__ xz, short* __restrict__ hz,
    int* __restrict__ flags, float* __restrict__ out) {
  __shared__ __align__(16) char zbuf[40960];   // 40 frags x 1KB
  __shared__ __align__(16) char htr[4096];     // [a 64][u_l 32] bf16

  const int bid = blockIdx.x;
  const int m = bid >> 5, g = bid & 31;
  const int dir = g & 1, bb = g >> 1;
  const int tid = threadIdx.x;
  const int w = tid >> 6, l = tid & 63;
  const int lg = l >> 4, ln = l & 15;

  // ---- prologue: pin W (10 frags = 40 VGPR) + bias via asm loads ----
  const char* wslice = (const char*)wf +
      ((((long)dir * 8 + m) * 8 + w) * 10) * 1024 + (long)l * 16;
  bf16x8 W0[10];
#pragma unroll
  for (int kt = 0; kt < 10; ++kt) W0[kt] = ald16(wslice + kt * 1024);
  const f32x4 bias4 = aldf4((const char*)bp +
      (((((long)dir * 8 + m) * 8 + w) * 64 + l) * 16));
  WAITV0;

  const char* xzb = (const char*)xz + (long)bb * (128L * 64 * 64 * 2);
  char* const hzg = (char*)hz + (long)g * (2L * 64 * 256 * 2);
  int* const flg = flags + g * T_LEN;

  float cst[4] = {0.f, 0.f, 0.f, 0.f};

  for (int st = 0; st < T_LEN; ++st) {
    const int t = dir ? (T_LEN - 1 - st) : st;

    // ---- acquire: partners' h(st-1) published ----
    if (st > 0 && tid == 0) {
      while (__hip_atomic_load(flg + (st - 1), __ATOMIC_RELAXED,
                               __HIP_MEMORY_SCOPE_AGENT) < 8)
        __builtin_amdgcn_s_sleep(2);
    }
    __syncthreads();

    // ---- stage z(t): wave w stages x-frag w (gll16) + h-frags 8+4w..8+4w+3
    //      (sc0sc1 reg loads -> ds_write; zeros at st=0) ----
    {
      const char* xstep = xzb + (long)t * (64 * 64 * 2);
      {
        const int f = w, kt = f >> 2, nt = f & 3;
        gll16(xstep + (long)(((nt * 16 + ln) * 64 + kt * 32 + lg * 8) * 2),
              zbuf + f * 1024);
      }
      bf16x8 hstg[4];
      if (st == 0) {
#pragma unroll
        for (int j = 0; j < 4; ++j) hstg[j] = (bf16x8)(short)0;
      } else {
        const char* hprev = hzg + (long)((st + 1) & 1) * (64 * 256 * 2);
#pragma unroll
        for (int j = 0; j < 4; ++j) {
          const int f = 8 + 4 * w + j, kt = f >> 2, nt = f & 3;
          hstg[j] = ald16_dev(
              hprev + (long)(((nt * 16 + ln) * 256 + (kt - 2) * 32 + lg * 8) * 2));
        }
      }
      WAITV0; SCHB;
#pragma unroll
      for (int j = 0; j < 4; ++j)
        *reinterpret_cast<bf16x8*>(zbuf + (8 + 4 * w + j) * 1024 + l * 16) = hstg[j];
    }
    __syncthreads();

    // ---- MFMA: 10 kt x 4 nt, W pinned, B from LDS ----
    f32x4 acc[4];
#pragma unroll
    for (int nt = 0; nt < 4; ++nt) acc[nt] = bias4;
#pragma unroll
    for (int kt = 0; kt < 10; ++kt)
#pragma unroll
      for (int nt = 0; nt < 4; ++nt) {
        bf16x8 b = *reinterpret_cast<const bf16x8*>(
            zbuf + (kt * 4 + nt) * 1024 + l * 16);
        acc[nt] = __builtin_amdgcn_mfma_f32_16x16x32_bf16(W0[kt], b, acc[nt], 0, 0, 0);
      }

    // ---- epilogue (lane-local: regs 0..3 = gates i,f,g,o) ----
    float hv[4];
#pragma unroll
    for (int nt = 0; nt < 4; ++nt) {
      float gi = sigmoidf_fast(acc[nt][0]);
      float gf = sigmoidf_fast(acc[nt][1]);
      float gg = tanhf_fast(acc[nt][2]);
      float go = sigmoidf_fast(acc[nt][3]);
      float cc = gf * cst[nt] + gi * gg;
      cst[nt] = cc;
      hv[nt] = go * tanhf_fast(cc);
    }
#pragma unroll
    for (int nt = 0; nt < 4; ++nt)
      *reinterpret_cast<short*>(htr + (nt * 16 + ln) * 64 + (4 * w + lg) * 2) =
          f32_to_bf16(hv[nt]);

    // out stores (normal; retire into local L2, drained by the publish WAITV0)
    {
      const long hrow = (long)dir * 256 + 32 * m + 4 * w + lg;
#pragma unroll
      for (int nt = 0; nt < 4; ++nt) {
        const int a = nt * 16 + ln;
        out[(((long)bb * 512 + hrow) * 128 + t) * 64 + a] = hv[nt];
      }
    }
    __syncthreads();   // htr complete

    // ---- publish h slice (sc0sc1 write-through) ----
    char* hcur = hzg + (long)(st & 1) * (64 * 256 * 2);
    if (tid < 256) {
      const int a = tid >> 2, seg = tid & 3;
      bf16x8 v = *reinterpret_cast<const bf16x8*>(htr + tid * 16);
      ast16_dev(hcur + (long)((a * 256 + 32 * m + seg * 8) * 2), v);
    }
    WAITV0;            // h (and out) stores at coherence point
    __syncthreads();   // all threads drained before flag post
    if (tid == 0)
      __hip_atomic_fetch_add(flg + st, 1, __ATOMIC_RELAXED,
                             __HIP_MEMORY_SCOPE_AGENT);
  }
}

// ---------------- launcher ----------------
extern "C" void kernel_launch(void* const* d_in, const int* in_sizes, int n_in,
                              void* d_out, int out_size, void* d_ws, size_t ws_size,
                              hipStream_t stream) {
  const float* x     = (const float*)d_in[0];
  const float* Wih_f = (const float*)d_in[1];
  const float* Whh_f = (const float*)d_in[2];
  const float* bih_f = (const float*)d_in[3];
  const float* bhh_f = (const float*)d_in[4];
  const float* Wih_b = (const float*)d_in[5];
  const float* Whh_b = (const float*)d_in[6];
  const float* bih_b = (const float*)d_in[7];
  const float* bhh_b = (const float*)d_in[8];
  float* out = (float*)d_out;

  char* ws = (char*)d_ws;
  short* wf    = (short*)(ws + WF_OFF);
  float* bp    = (float*)(ws + BI_OFF);
  short* xz    = (short*)(ws + XZ_OFF);
  short* hz    = (short*)(ws + HZ_OFF);
  int*   flags = (int*)(ws + FL_OFF);

  hipLaunchKernelGGL(pack_w, dim3(320), dim3(256), 0, stream,
                     Wih_f, Whh_f, Wih_b, Whh_b, wf);
  hipLaunchKernelGGL(pack_bias, dim3(32), dim3(256), 0, stream,
                     bih_f, bhh_f, bih_b, bhh_b, bp);
  hipLaunchKernelGGL(pack_x, dim3(4096), dim3(256), 0, stream, x, xz);
  // zero flags only (hz is write-before-read inside lstm_rec; st=0 uses
  // literal zeros so no memset-staleness hazard on the sc-bypass read path)
  hipMemsetAsync(ws + FL_OFF, 0, WS_END - FL_OFF, stream);
  hipLaunchKernelGGL(lstm_rec, dim3(256), dim3(512), 0, stream,
                     wf, bp, xz, hz, flags, out);
}